// Round 1
// baseline (103.040 us; speedup 1.0000x reference)
//
#include <hip/hip_runtime.h>
#include <hip/hip_bf16.h>

// ControlledSystem RHS: per-element ODE derivative with tiny MLP friction model.
// N = 1<<20, H = 64. All fp32.
//
// Physical constants (from reference):
#define M1_C 1.0f
#define M2_INV (1.0f / 1.5f)
#define K1_C 2.0f
#define K2_C 3.0f
#define C1_C 0.5f
#define C2_C 0.8f
#define KARNOPP_DV 0.01f
#define REF_AMP 0.5f
#define REF_OMEGA 0.5f
#define HDIM 64

#define LOG2E 1.4426950408889634f
#define LN2 0.6931471805599453f

// tanh(x) = 1 - 2/(exp(2x)+1), via v_exp_f32 (exp2) + v_rcp_f32.
// Saturates correctly for large |x| (rcp(inf)=0 -> 1; exp2->0 -> -1).
__device__ __forceinline__ float tanh_fast(float x) {
    float e = __builtin_amdgcn_exp2f(x * (2.0f * LOG2E));   // exp(2x)
    float r = __builtin_amdgcn_rcpf(e + 1.0f);
    return fmaf(-2.0f, r, 1.0f);
}

// softplus(x) = max(x,0) + ln(1 + exp(-|x|)) — numerically stable.
__device__ __forceinline__ float softplus_fast(float x) {
    float ax = fabsf(x);
    float e = __builtin_amdgcn_exp2f(-ax * LOG2E);          // exp(-|x|)
    float l = __builtin_amdgcn_logf(1.0f + e) * LN2;        // ln(1+e)
    return fmaxf(x, 0.0f) + l;
}

__global__ __launch_bounds__(256) void controlled_system_kernel(
    const float* __restrict__ t,
    const float* __restrict__ z,
    const float* __restrict__ logK,
    const float* __restrict__ logz,
    const float* __restrict__ logp,
    const float* __restrict__ W1,
    const float* __restrict__ b1,
    const float* __restrict__ W2,
    const float* __restrict__ b2,
    float* __restrict__ out,
    int N)
{
    // Stage MLP weights into LDS, interleaved per hidden unit:
    // wpack[j] = { W1[j], b1[j], W2[j][0], W2[j][1] }
    __shared__ float4 wpack[HDIM];
    __shared__ float sb2[2];

    int tid = threadIdx.x;
    if (tid < HDIM) {
        wpack[tid] = make_float4(W1[tid], b1[tid], W2[2 * tid], W2[2 * tid + 1]);
    }
    if (tid < 2) sb2[tid] = b2[tid];
    __syncthreads();

    int i = blockIdx.x * blockDim.x + tid;
    if (i >= N) return;

    // Uniform scalar params (broadcast loads; exp computed once per thread, cheap)
    float K  = __builtin_amdgcn_exp2f(logK[0] * LOG2E);
    float zc = __builtin_amdgcn_exp2f(logz[0] * LOG2E);
    float pc = __builtin_amdgcn_exp2f(logp[0] * LOG2E);

    float tt = t[i];
    float x1 = z[i];
    float v1 = z[N + i];
    float x2 = z[2 * N + i];
    float v2 = z[3 * N + i];
    float xc = z[4 * N + i];

    float x2_ref = REF_AMP * __sinf(REF_OMEGA * tt);
    float e_ctl = x2_ref - x2;
    float d_xc = fmaf(-pc, xc, e_ctl);
    float u = K * (zc - pc) * xc + K * e_ctl;

    float dx12 = x1 - x2;
    float dv12 = v1 - v2;

    float dv1 = u - K1_C * x1 - C1_C * v1 - K2_C * dx12 - C2_C * dv12;  // / M1 == 1

    float F_net = fmaf(K2_C, dx12, C2_C * dv12);

    // MLP: h = tanh(v2*W1 + b1); out = h @ W2 + b2
    float a0 = sb2[0];
    float a1 = sb2[1];
#pragma unroll
    for (int j = 0; j < HDIM; ++j) {
        float4 w = wpack[j];
        float h = tanh_fast(fmaf(v2, w.x, w.y));
        a0 = fmaf(h, w.z, a0);
        a1 = fmaf(h, w.w, a1);
    }
    float kinetic_mag    = softplus_fast(a0);
    float stiction_limit = softplus_fast(a1);

    bool is_static = fabsf(v2) < KARNOPP_DV;
    float F_static = -fminf(fmaxf(F_net, -stiction_limit), stiction_limit);
    // sign(v2): only consumed when |v2| >= KARNOPP_DV, so v2 != 0 there.
    float F_kinetic = (v2 > 0.0f) ? -kinetic_mag : kinetic_mag;
    float F_friction = is_static ? F_static : F_kinetic;
    float dv2 = (F_net + F_friction) * M2_INV;

    out[i]         = v1;     // dx1_dt
    out[N + i]     = dv1;    // dv1_dt
    out[2 * N + i] = v2;     // dx2_dt
    out[3 * N + i] = dv2;    // dv2_dt
    out[4 * N + i] = d_xc;   // d_xc
}

extern "C" void kernel_launch(void* const* d_in, const int* in_sizes, int n_in,
                              void* d_out, int out_size, void* d_ws, size_t ws_size,
                              hipStream_t stream) {
    const float* t    = (const float*)d_in[0];
    const float* z    = (const float*)d_in[1];
    const float* logK = (const float*)d_in[2];
    const float* logz = (const float*)d_in[3];
    const float* logp = (const float*)d_in[4];
    const float* W1   = (const float*)d_in[5];
    const float* b1   = (const float*)d_in[6];
    const float* W2   = (const float*)d_in[7];
    const float* b2   = (const float*)d_in[8];
    float* out = (float*)d_out;

    int N = in_sizes[0];
    int blocks = (N + 255) / 256;
    controlled_system_kernel<<<blocks, 256, 0, stream>>>(
        t, z, logK, logz, logp, W1, b1, W2, b2, out, N);
}